// Round 6
// baseline (208.833 us; speedup 1.0000x reference)
//
#include <hip/hip_runtime.h>

// Conv 3x3 VALID + ReLU over 262144 independent 16x8 fp32 images.
// Streaming op: 134 MB in + 88 MB out (~36us/CU floor @ 6.3 TB/s).
// Structure: wave-independent pipelines (private LDS slice, NO
// __syncthreads). NEW this round: per-wave NC=4 chunk pipeline — after
// staging chunk t into LDS, issue chunk t+1's 8 nt loads immediately so
// HBM latency hides under compute+store (round-5 was one-shot per block:
// every wave paid ~900cy load latency serially).
// Row split {4,3,4,3} keeps all LDS b128 traffic <=2-way per octet (free).
// Nontemporal global access dodges L3-resident dirty poison writeback.

#define BLOCK 256
#define IPW   16                 // images per wave (4 threads / image)
#define STRIDE 132               // floats per image in LDS (conflict-free w/ {4,3,4,3})
#define SLICE (IPW * STRIDE)     // 2112 floats = 8448 B per wave
#define NC    4                  // chunks (of 64 images) per block
#define NIMG_TOTAL (4096 * 64)

// native clang vectors: __builtin_nontemporal_* accepts these (not HIP float4)
typedef float f32x4 __attribute__((ext_vector_type(4)));
typedef float f32x2 __attribute__((ext_vector_type(2)));

// wave-level LDS fence: all outstanding DS ops retired; no workgroup barrier.
#define FENCE_LDS() do { \
    asm volatile("s_waitcnt lgkmcnt(0)" ::: "memory"); \
    __builtin_amdgcn_wave_barrier(); \
} while (0)

__global__ __launch_bounds__(BLOCK, 4) void conv3x3_relu_kernel(
    const float* __restrict__ x,
    const float* __restrict__ kern,
    float* __restrict__ out)
{
    __shared__ float s[4 * SLICE];   // 33792 B -> 4 blocks/CU, 16 waves/CU

    const int tid  = threadIdx.x;
    const int wid  = tid >> 6;
    const int lane = tid & 63;
    float* sw = &s[wid * SLICE];     // wave-private slice

    const float k00 = kern[0], k01 = kern[1], k02 = kern[2];
    const float k10 = kern[3], k11 = kern[4], k12 = kern[5];
    const float k20 = kern[6], k21 = kern[7], k22 = kern[8];

    // per-image thread mapping (constant across chunks)
    const int img  = lane >> 2;
    const int tq   = lane & 3;
    const int rs   = tq * 4 - (tq >> 1);   // {0,4,7,11}
    const int rcnt = 4 - (tq & 1);         // {4,3,4,3}

    // wave's image base for chunk 0
    const long long ib0 = (long long)blockIdx.x * (64 * NC) + wid * IPW;
    const f32x4* x4 = reinterpret_cast<const f32x4*>(x);

    f32x4 pf[8];   // single prefetch buffer; DS reads VGPRs at issue, so
                   // next-chunk loads may retarget pf right after ds_writes.

    // ---- prologue: issue chunk-0 loads ----
    {
        const f32x4* src = x4 + ib0 * 32;
        #pragma unroll
        for (int k = 0; k < 8; ++k)
            pf[k] = __builtin_nontemporal_load(&src[k * 64 + lane]);
    }

    #pragma unroll
    for (int t = 0; t < NC; ++t) {
        const long long ibt = ib0 + (long long)t * 64;

        // ---- stage chunk t into wave-private LDS (b128, conflict-free) ----
        #pragma unroll
        for (int k = 0; k < 8; ++k) {
            const int f  = k * 64 + lane;
            const int im = f >> 5;           // local image 0..15
            const int o4 = f & 31;
            *reinterpret_cast<f32x4*>(&sw[im * STRIDE + o4 * 4]) = pf[k];
        }

        // ---- issue chunk t+1 loads (in flight across compute+store) ----
        if (t + 1 < NC) {
            const f32x4* src = x4 + (ibt + 64) * 32;
            #pragma unroll
            for (int k = 0; k < 8; ++k)
                pf[k] = __builtin_nontemporal_load(&src[k * 64 + lane]);
        }
        FENCE_LDS();   // staging writes visible to our ds_reads

        // ---- compute: 4 threads/image, row split {4,3,4,3} ----
        const float* ip = &sw[img * STRIDE];
        float w[3][8];
        float acc[4][6];
        *reinterpret_cast<f32x4*>(&w[0][0]) = *reinterpret_cast<const f32x4*>(ip + rs * 8);
        *reinterpret_cast<f32x4*>(&w[0][4]) = *reinterpret_cast<const f32x4*>(ip + rs * 8 + 4);
        *reinterpret_cast<f32x4*>(&w[1][0]) = *reinterpret_cast<const f32x4*>(ip + (rs + 1) * 8);
        *reinterpret_cast<f32x4*>(&w[1][4]) = *reinterpret_cast<const f32x4*>(ip + (rs + 1) * 8 + 4);
        #pragma unroll
        for (int rr = 0; rr < 4; ++rr) {
            if (rr < rcnt) {
                float* wn = w[(rr + 2) % 3];
                *reinterpret_cast<f32x4*>(&wn[0]) =
                    *reinterpret_cast<const f32x4*>(ip + (rs + rr + 2) * 8);
                *reinterpret_cast<f32x4*>(&wn[4]) =
                    *reinterpret_cast<const f32x4*>(ip + (rs + rr + 2) * 8 + 4);
                const float* r0 = w[rr % 3];
                const float* r1 = w[(rr + 1) % 3];
                const float* r2 = wn;
                #pragma unroll
                for (int c = 0; c < 6; ++c) {
                    float a = r0[c] * k00 + r0[c + 1] * k01 + r0[c + 2] * k02
                            + r1[c] * k10 + r1[c + 1] * k11 + r1[c + 2] * k12
                            + r2[c] * k20 + r2[c + 1] * k21 + r2[c + 2] * k22;
                    acc[rr][c] = fmaxf(a, 0.0f);
                }
            }
        }
        FENCE_LDS();   // input reads retired before slice reuse

        // ---- stage outputs (16 img * 84 floats; even offsets -> b64) ----
        #pragma unroll
        for (int rr = 0; rr < 4; ++rr) {
            if (rr < rcnt) {
                float* op = &sw[img * 84 + (rs + rr) * 6];
                f32x2 v01; v01.x = acc[rr][0]; v01.y = acc[rr][1];
                f32x2 v23; v23.x = acc[rr][2]; v23.y = acc[rr][3];
                f32x2 v45; v45.x = acc[rr][4]; v45.y = acc[rr][5];
                *reinterpret_cast<f32x2*>(op)     = v01;
                *reinterpret_cast<f32x2*>(op + 2) = v23;
                *reinterpret_cast<f32x2*>(op + 4) = v45;
            }
        }
        FENCE_LDS();

        // ---- coalesced nt store (1344 floats = 336 float4 / wave) ----
        f32x4* dst = reinterpret_cast<f32x4*>(out + ibt * 84);
        const f32x4* s4 = reinterpret_cast<const f32x4*>(sw);
        #pragma unroll
        for (int k = 0; k < 6; ++k) {
            const int f = k * 64 + lane;
            if (f < 336) __builtin_nontemporal_store(s4[f], &dst[f]);
        }
        FENCE_LDS();   // store-feeding ds_reads retired before next staging
    }
}

extern "C" void kernel_launch(void* const* d_in, const int* in_sizes, int n_in,
                              void* d_out, int out_size, void* d_ws, size_t ws_size,
                              hipStream_t stream) {
    const float* x    = (const float*)d_in[0];
    const float* kern = (const float*)d_in[1];
    float* out        = (float*)d_out;
    const int nblocks = NIMG_TOTAL / (64 * NC);   // 1024
    conv3x3_relu_kernel<<<nblocks, BLOCK, 0, stream>>>(x, kern, out);
}